// Round 10
// baseline (149.899 us; speedup 1.0000x reference)
//
#include <hip/hip_runtime.h>

using bf16x8 = __attribute__((ext_vector_type(8))) __bf16;
using f32x4  = __attribute__((ext_vector_type(4))) float;
using f32x16 = __attribute__((ext_vector_type(16))) float;

__device__ __forceinline__ unsigned short f2bf(float f) {
  unsigned u = __builtin_bit_cast(unsigned, f);
  u += 0x7fffu + ((u >> 16) & 1u);
  return (unsigned short)(u >> 16);
}

__device__ __forceinline__ unsigned cvt_pk_bf16(float lo, float hi) {
  unsigned r;
  asm("v_cvt_pk_bf16_f32 %0, %1, %2" : "=v"(r) : "v"(lo), "v"(hi));
  return r;
}

// v_permlane32_swap_b32: a = {a.lo-half, b.lo-half}, b = {a.hi-half, b.hi-half}.
__device__ __forceinline__ void permswap(unsigned &a, unsigned &b) {
  asm("v_permlane32_swap_b32 %0, %1" : "+v"(a), "+v"(b));
}

__device__ __forceinline__ void gload_lds16(const void* g, void* l) {
  __builtin_amdgcn_global_load_lds((const __attribute__((address_space(1))) void*)g,
                                   (__attribute__((address_space(3))) void*)l, 16, 0, 0);
}

// ---------------- fused prep: x fp32->bf16 + W_attn/W_proj transpose+convert ----------------
__global__ void prep_kernel(const float* __restrict__ x, unsigned short* __restrict__ xb,
                            const float* __restrict__ Wa, unsigned short* __restrict__ WaT,
                            const float* __restrict__ Wp, unsigned short* __restrict__ WpT) {
  __shared__ float tile[32][33];
  const int bid = blockIdx.x;
  const int tid = threadIdx.x;
  if (bid < 8192) {
    int i = (bid * 256 + tid) * 4;
    float4 f = *(const float4*)(x + i);
    ushort4 o;
    o.x = f2bf(f.x); o.y = f2bf(f.y); o.z = f2bf(f.z); o.w = f2bf(f.w);
    *(ushort4*)(xb + i) = o;
    return;
  }
  const float* W; unsigned short* WT; int N, tb;
  if (bid < 11264) { W = Wa; WT = WaT; N = 3072; tb = bid - 8192; }
  else             { W = Wp; WT = WpT; N = 1024; tb = bid - 11264; }
  const int nt = N >> 5;
  const int n0 = (tb % nt) * 32, k0 = (tb / nt) * 32;
  const int tx = tid & 31, ty = tid >> 5;
  #pragma unroll
  for (int i = 0; i < 32; i += 8)
    tile[ty + i][tx] = W[(size_t)(k0 + ty + i) * N + (n0 + tx)];
  __syncthreads();
  #pragma unroll
  for (int i = 0; i < 32; i += 8)
    WT[(size_t)(n0 + ty + i) * 1024 + (k0 + tx)] = f2bf(tile[tx][ty + i]);
}

// ================ GEMM 256x128, BK=64, 8 waves, counted vmcnt (R8 schedule) ================
// K = 1024. MODE 0 (grid 24x32): bn 0-7 q (pre-scaled), 8-15 k, 16-23 V -> vT bounce.
// MODE 1 (grid 8x32): fp32 store to Cout[M][N], N=1024.
template <int MODE>
__global__ __launch_bounds__(512, 1)
void gemm256x128(const unsigned short* __restrict__ A,
                 const unsigned short* __restrict__ BT,
                 float* __restrict__ Cout,
                 unsigned short* __restrict__ q_out,
                 unsigned short* __restrict__ k_out,
                 unsigned short* __restrict__ v_out) {
  constexpr int K = 1024;
  __shared__ alignas(16) char smem[98304];   // A: buf*32768 @0; B: 65536 + buf*16384

  const int tid = threadIdx.x;
  const int lane = tid & 63, w = tid >> 6;
  const int wm = w >> 1, wn = w & 1;          // 4x2 wave grid, 64x64 per wave
  const int l15 = lane & 15, l4 = lane >> 4;
  const int bm = blockIdx.y, bn = blockIdx.x;

  // staging: row = j*64 + (tid>>3); 8 thr x 16B per row; source chunk swizzled
  const int srow = tid >> 3;                      // 0..63
  const int schunk = ((tid & 7) ^ (srow & 7)) * 8;
  const unsigned short* pa = A + (size_t)(bm * 256 + srow) * K + schunk;
  const unsigned short* pb = BT + (size_t)(bn * 128 + srow) * K + schunk;
  const int sdst = w * 1024;

  f32x4 acc[4][4] = {};

#define GLA(j, buf, tcol) gload_lds16(pa + (size_t)(j) * 64 * K + (tcol), \
                                      smem + (buf) * 32768 + (j) * 8192 + sdst)
#define GLB(j, buf, tcol) gload_lds16(pb + (size_t)(j) * 64 * K + (tcol), \
                                      smem + 65536 + (buf) * 16384 + (j) * 8192 + sdst)

  // prologue: tile 0 -> buf 0 (6 loads/thread)
  GLA(0, 0, 0); GLA(1, 0, 0); GLA(2, 0, 0); GLA(3, 0, 0);
  GLB(0, 0, 0); GLB(1, 0, 0);

  for (int t = 0; t < 16; t++) {
    const int cur = t & 1, nxt = cur ^ 1;
    const int tcol = (t + 1) * 64;
    const bool more = (t < 15);

    __builtin_amdgcn_s_barrier();            // everyone done reading buf[nxt]
    if (more) { GLA(0, nxt, tcol); GLA(1, nxt, tcol); }
    if (more) asm volatile("s_waitcnt vmcnt(2)" ::: "memory");
    else      asm volatile("s_waitcnt vmcnt(0)" ::: "memory");
    __builtin_amdgcn_s_barrier();            // tile t visible to all waves
    __builtin_amdgcn_sched_barrier(0);

    const char* Ab = smem + cur * 32768;
    const char* Bb = smem + 65536 + cur * 16384;

    // B fragments (live across both phases)
    bf16x8 bf[4][2];
    #pragma unroll
    for (int nf = 0; nf < 4; nf++) {
      int rowb = wn * 64 + nf * 16 + l15;
      #pragma unroll
      for (int kc = 0; kc < 2; kc++)
        bf[nf][kc] = *(const bf16x8*)(Bb + rowb * 128 + (((kc * 4 + l4) ^ (rowb & 7)) << 4));
    }
    bf16x8 a0[2][2], a1[2][2];
    #pragma unroll
    for (int i = 0; i < 2; i++) {
      int rowa = wm * 64 + i * 16 + l15;
      #pragma unroll
      for (int kc = 0; kc < 2; kc++)
        a0[i][kc] = *(const bf16x8*)(Ab + rowa * 128 + (((kc * 4 + l4) ^ (rowa & 7)) << 4));
    }

#define LDA(dst, mfb)                                                            \
    _Pragma("unroll")                                                            \
    for (int i = 0; i < 2; i++) {                                                \
      int rowa = wm * 64 + ((mfb) + i) * 16 + l15;                               \
      _Pragma("unroll")                                                          \
      for (int kc = 0; kc < 2; kc++)                                             \
        dst[i][kc] = *(const bf16x8*)(Ab + rowa * 128 + (((kc * 4 + l4) ^ (rowa & 7)) << 4)); \
    }
#define MFMA16(mb, af)                                                           \
    __builtin_amdgcn_s_setprio(1);                                               \
    _Pragma("unroll")                                                            \
    for (int m = 0; m < 2; m++)                                                  \
      _Pragma("unroll")                                                          \
      for (int nf = 0; nf < 4; nf++) {                                           \
        acc[(mb) + m][nf] = __builtin_amdgcn_mfma_f32_16x16x32_bf16(af[m][0], bf[nf][0], acc[(mb) + m][nf], 0, 0, 0); \
        acc[(mb) + m][nf] = __builtin_amdgcn_mfma_f32_16x16x32_bf16(af[m][1], bf[nf][1], acc[(mb) + m][nf], 0, 0, 0); \
      }                                                                          \
    __builtin_amdgcn_s_setprio(0);                                               \
    __builtin_amdgcn_sched_barrier(0);

    // ph0: prefetch A mf2-3; issue remaining 4 staged loads; compute mf0-1
    LDA(a1, 2);
    if (more) { GLA(2, nxt, tcol); GLA(3, nxt, tcol); GLB(0, nxt, tcol); GLB(1, nxt, tcol); }
    MFMA16(0, a0);
    // ph1: compute mf2-3
    MFMA16(2, a1);
#undef LDA
#undef MFMA16
  }
#undef GLA
#undef GLB

  if (MODE == 1) {
    #pragma unroll
    for (int mf = 0; mf < 4; mf++)
      #pragma unroll
      for (int nf = 0; nf < 4; nf++)
        #pragma unroll
        for (int r = 0; r < 4; r++) {
          int m = bm * 256 + wm * 64 + mf * 16 + l4 * 4 + r;
          int n = bn * 128 + wn * 64 + nf * 16 + l15;
          Cout[(size_t)m * 1024 + n] = acc[mf][nf][r];
        }
  } else if (bn < 16) {
    // ---- q/k scatter, head-major; q pre-scaled by (1/8)*log2e ----
    const float qsc = (bn < 8) ? 0.18033688f : 1.0f;
    unsigned short* dst = (bn < 8) ? q_out : k_out;
    #pragma unroll
    for (int mf = 0; mf < 4; mf++) {
      #pragma unroll
      for (int nf = 0; nf < 4; nf++) {
        #pragma unroll
        for (int r = 0; r < 4; r++) {
          int m = bm * 256 + wm * 64 + mf * 16 + l4 * 4 + r;
          int n = bn * 128 + wn * 64 + nf * 16 + l15;
          int h = (n >> 6) & 15, d = n & 63;
          dst[((size_t)((m >> 11) * 16 + h) * 2048 + (m & 2047)) * 64 + d] =
              f2bf(acc[mf][nf][r] * qsc);
        }
      }
    }
  } else {
    // ---- V region: bounce 256x128 through LDS -> vT[bh][d][t] ----
    __syncthreads();
    unsigned short* tt = (unsigned short*)smem;   // [128 cols][256 rows], row ^ ((col&7)<<3)
    #pragma unroll
    for (int mf = 0; mf < 4; mf++)
      #pragma unroll
      for (int nf = 0; nf < 4; nf++)
        #pragma unroll
        for (int r = 0; r < 4; r++) {
          int row_l = wm * 64 + mf * 16 + l4 * 4 + r;
          int cl = wn * 64 + nf * 16 + l15;
          tt[cl * 256 + (row_l ^ ((cl & 7) << 3))] = f2bf(acc[mf][nf][r]);
        }
    __syncthreads();
    const int b_ = bm >> 3;
    const int t0 = (bm & 7) * 256;
    const int mm = (tid & 31) * 8;
    #pragma unroll
    for (int p = 0; p < 8; p++) {
      int cl = p * 16 + (tid >> 5);
      int4 val = *(const int4*)&tt[cl * 256 + (mm ^ ((cl & 7) << 3))];
      int vh = (bn - 16) * 128 + cl;
      int h = vh >> 6, d = vh & 63;
      *(int4*)(v_out + ((size_t)(b_ * 16 + h) * 64 + d) * 2048 + t0 + mm) = val;
    }
  }
}

// Repack one 16-reg C-layout block (32 keys x q) into two PV A-frags.
__device__ __forceinline__ void repack_pa(const f32x16 s, bf16x8 &fl, bf16x8 &fh) {
  unsigned p01 = cvt_pk_bf16(s[0], s[1]);
  unsigned p23 = cvt_pk_bf16(s[2], s[3]);
  unsigned p45 = cvt_pk_bf16(s[4], s[5]);
  unsigned p67 = cvt_pk_bf16(s[6], s[7]);
  unsigned p89 = cvt_pk_bf16(s[8], s[9]);
  unsigned pAB = cvt_pk_bf16(s[10], s[11]);
  unsigned pCD = cvt_pk_bf16(s[12], s[13]);
  unsigned pEF = cvt_pk_bf16(s[14], s[15]);
  permswap(p01, p45);
  permswap(p23, p67);
  permswap(p89, pCD);
  permswap(pAB, pEF);
  uint4 f0, f1;
  f0.x = p01; f0.y = p23; f0.z = p45; f0.w = p67;
  f1.x = p89; f1.y = pAB; f1.z = pCD; f1.w = pEF;
  fl = __builtin_bit_cast(bf16x8, f0);
  fh = __builtin_bit_cast(bf16x8, f1);
}

// ---------------- flash attention (R7, unchanged) ----------------
__global__ __launch_bounds__(256, 4)
void attn_kernel(const unsigned short* __restrict__ q,
                 const unsigned short* __restrict__ k,
                 const unsigned short* __restrict__ vT,
                 unsigned short* __restrict__ att) {
  __shared__ alignas(16) char smem[32768];   // K: [2][8192] @0, V^T: [2][8192] @16384

  const int bid = blockIdx.x;
  const int qt = 15 - (bid >> 6);
  const int bh = bid & 63;
  const int tid = threadIdx.x;
  const int lane = tid & 63, w = tid >> 6;
  const int l31 = lane & 31, hi = lane >> 5;
  const size_t base = (size_t)bh * 2048 * 64;

  bf16x8 qf[4];
  const int qwb = qt * 128 + w * 32;
  const int qrow = qwb + l31;
  #pragma unroll
  for (int ks = 0; ks < 4; ks++)
    qf[ks] = *(const bf16x8*)(q + base + (size_t)qrow * 64 + ks * 16 + hi * 8);
  asm volatile("" :: "v"(qf[0]), "v"(qf[1]), "v"(qf[2]), "v"(qf[3]));

  const char* kb4[4];
  #pragma unroll
  for (int ks = 0; ks < 4; ks++)
    kb4[ks] = smem + l31 * 128 + (((2 * ks + hi) ^ (l31 & 7)) << 4);

  const int srow = w * 8 + (lane >> 3);
  const int sc8 = ((lane & 7) ^ (srow & 7)) * 8;

  f32x16 o0 = {}, o1 = {}, lacc = {};
  const int qmax = qwb + 31;
  const int ntiles = 2 * qt + 2;

  uint4 onesw;
  onesw.x = 0x3F803F80u; onesw.y = 0x3F803F80u; onesw.z = 0x3F803F80u; onesw.w = 0x3F803F80u;
  const bf16x8 onesv = __builtin_bit_cast(bf16x8, onesw);

  {
    const unsigned short* kp = k + base + srow * 64 + sc8;
    gload_lds16(kp,         smem + w * 1024);
    gload_lds16(kp + 2048,  smem + 4096 + w * 1024);
    const unsigned short* vp = vT + base + (size_t)srow * 2048 + sc8;
    gload_lds16(vp,          smem + 16384 + w * 1024);
    gload_lds16(vp + 65536,  smem + 16384 + 4096 + w * 1024);
  }
  const unsigned short* kq1 = k + base + srow * 64 + sc8 + 4096;
  const unsigned short* kq2 = kq1 + 4096;
  const unsigned short* vq1 = vT + base + (size_t)srow * 2048 + sc8 + 64;
  const unsigned short* vq2 = vq1 + 64;

#define COMPUTE_TILE(BUF, KBASE)                                               \
  do {                                                                         \
    const int kbase_ = (KBASE);                                                \
    if (kbase_ <= qmax) {                                                      \
      f32x16 s0 = {}, s1 = {};                                                 \
      __builtin_amdgcn_s_setprio(1);                                           \
      _Pragma("unroll")                                                        \
      for (int ks = 0; ks < 4; ks++) {                                         \
        bf16x8 k0 = *(const bf16x8*)(kb4[ks] + (BUF));                         \
        bf16x8 k1 = *(const bf16x8*)(kb4[ks] + (BUF) + 4096);                  \
        s0 = __builtin_amdgcn_mfma_f32_32x32x16_bf16(k0, qf[ks], s0, 0, 0, 0); \
        s1 = __builtin_amdgcn_mfma_f32_32x32x16_bf16(k1, qf[ks], s1, 0, 0, 0); \
      }                                                                        \
      __builtin_amdgcn_s_setprio(0);                                           \
      if (kbase_ + 63 > qwb) {                                                 \
        _Pragma("unroll")                                                      \
        for (int r = 0; r < 16; r++) {                                         \
          int crow = (r & 3) + 8 * (r >> 2) + 4 * hi;                          \
          if (kbase_ + crow > qrow) s0[r] = -1e30f;                            \
          if (kbase_ + 32 + crow > qrow) s1[r] = -1e30f;                       \
        }                                                                      \
      }                                                                        \
      _Pragma("unroll")                                                        \
      for (int r = 0; r < 16; r++) {                                           \
        float t0_ = s0[r], t1_ = s1[r];                                        \
        asm("v_exp_f32 %0, %0" : "+v"(t0_));                                   \
        asm("v_exp_f32 %0, %0" : "+v"(t1_));                                   \
        s0[r] = t0_; s1[r] = t1_;                                              \
      }                                                                        \
      bf16x8 pa[4];                                                            \
      repack_pa(s0, pa[0], pa[1]);                                             \
      repack_pa(s1, pa[2], pa[3]);                                             \
      __builtin_amdgcn_s_setprio(1);                                           \
      _Pragma("unroll")                                                        \
      for (int ks = 0; ks < 4; ks++) {                                         \
        bf16x8 vf0 = *(const bf16x8*)(kb4[ks] + 16384 + (BUF));                \
        bf16x8 vf1 = *(const bf16x8*)(kb4[ks] + 16384 + (BUF) + 4096);         \
        o0 = __builtin_amdgcn_mfma_f32_32x32x16_bf16(pa[ks], vf0, o0, 0, 0, 0);\
        o1 = __builtin_amdgcn_mfma_f32_32x32x16_bf16(pa[ks], vf1, o1, 0, 0, 0);\
        lacc = __builtin_amdgcn_mfma_f32_32x32x16_bf16(pa[ks], onesv, lacc, 0, 0, 0);\
      }                                                                        \
      __builtin_amdgcn_s_setprio(0);                                           \
    }                                                                          \
  } while (0)

  for (int t = 0; t < ntiles; t += 2) {
    gload_lds16(kq1,         smem + 8192 + w * 1024);
    gload_lds16(kq1 + 2048,  smem + 8192 + 4096 + w * 1024);
    gload_lds16(vq1,         smem + 16384 + 8192 + w * 1024);
    gload_lds16(vq1 + 65536, smem + 16384 + 8192 + 4096 + w * 1024);
    kq1 += 8192; vq1 += 128;
    asm volatile("s_waitcnt vmcnt(4)" ::: "memory");
    __builtin_amdgcn_s_barrier();
    __builtin_amdgcn_sched_barrier(0);
    COMPUTE_TILE(0, t * 64);
    __builtin_amdgcn_s_barrier();
    __builtin_amdgcn_sched_barrier(0);

    if (t + 2 < ntiles) {
      gload_lds16(kq2,         smem + w * 1024);
      gload_lds16(kq2 + 2048,  smem + 4096 + w * 1024);
      gload_lds16(vq2,         smem + 16384 + w * 1024);
      gload_lds16(vq2 + 65536, smem + 16384 + 4096 + w * 1024);
      kq2 += 8192; vq2 += 128;
      asm volatile("s_waitcnt vmcnt(4)" ::: "memory");
    } else {
      asm volatile("s_waitcnt vmcnt(0)" ::: "memory");
    }
    __builtin_amdgcn_s_barrier();
    __builtin_amdgcn_sched_barrier(0);
    COMPUTE_TILE(8192, t * 64 + 64);
    __builtin_amdgcn_s_barrier();
    __builtin_amdgcn_sched_barrier(0);
  }
#undef COMPUTE_TILE

  const int b_ = bh >> 4, h = bh & 15;
  #pragma unroll
  for (int r = 0; r < 16; r++) {
    int crow = (r & 3) + 8 * (r >> 2) + 4 * hi;
    float li = 1.0f / lacc[r];
    int t = qt * 128 + w * 32 + crow;
    size_t rb = ((size_t)(b_ * 2048 + t)) * 1024 + h * 64;
    att[rb + l31] = f2bf(o0[r] * li);
    att[rb + 32 + l31] = f2bf(o1[r] * li);
  }
}

// ---------------- launch ----------------
extern "C" void kernel_launch(void* const* d_in, const int* in_sizes, int n_in,
                              void* d_out, int out_size, void* d_ws, size_t ws_size,
                              hipStream_t stream) {
  const float* x  = (const float*)d_in[0];   // [4,2048,1024]
  const float* Wa = (const float*)d_in[1];   // [1024,3072]
  const float* Wp = (const float*)d_in[2];   // [1024,1024]
  float* out = (float*)d_out;                // [4,2048,1024] fp32
  char* ws = (char*)d_ws;

  unsigned short* xb  = (unsigned short*)(ws);                 // 16 MB
  unsigned short* WaT = (unsigned short*)(ws + 16777216);      // 6 MB
  unsigned short* WpT = (unsigned short*)(ws + 23068672);      // 2 MB
  unsigned short* qb  = (unsigned short*)(ws + 25165824);      // 16 MB
  unsigned short* kb  = (unsigned short*)(ws + 41943040);      // 16 MB
  unsigned short* vtb = (unsigned short*)(ws + 58720256);      // 16 MB (vT[bh][d][t])
  unsigned short* att = xb;                                    // reuse xb after GEMM1

  prep_kernel<<<12288, 256, 0, stream>>>(x, xb, Wa, WaT, Wp, WpT);

  gemm256x128<0><<<dim3(24, 32), 512, 0, stream>>>(xb, WaT, nullptr, qb, kb, vtb);

  attn_kernel<<<1024, 256, 0, stream>>>(qb, kb, vtb, att);

  gemm256x128<1><<<dim3(8, 32), 512, 0, stream>>>(att, WpT, out, nullptr, nullptr, nullptr);
}